// Round 2
// baseline (271.379 us; speedup 1.0000x reference)
//
#include <hip/hip_runtime.h>
#include <hip/hip_bf16.h>

typedef __attribute__((ext_vector_type(8))) short bf16x8;
typedef __attribute__((ext_vector_type(4))) float f32x4;

// xft NHWC: index ((b*65 + h)*65 + w)*256 + c   (16x65x65x256 bf16 = 34.6 MB)
#define XT_ELEMS 17305600
#define OUT_PER_B (256 * 1024)

static __device__ __forceinline__ ushort f2bf(float f) {
  union { float f; unsigned int i; } v; v.f = f;
  unsigned int x = v.i;
  x += 0x7fffu + ((x >> 16) & 1u);   // round-to-nearest-even
  return (ushort)(x >> 16);
}

// ---------------- Kernel 1: separable 4x4 FIR, pad 2, f32 NCHW -> bf16 NHWC -----
// block = (b, h-tile of 5 output rows, 128-channel half); 8 chunks of 16 channels.
__global__ __launch_bounds__(256) void k_fir_nhwc(const float* __restrict__ x,
                                                  ushort* __restrict__ xft) {
  __shared__ float sx[16 * 8 * 64];      // [c][r][w]  input rows (h0-2 .. h0+5)
  __shared__ float st[16 * 529];         // [c][r*66 + jw], c-stride 529 (conflict-free)
  const int bid = blockIdx.x;            // 16*13*2 = 416
  const int b = bid / 26;
  const int rem = bid - b * 26;
  const int ht = rem >> 1, ch = rem & 1;
  const int h0 = ht * 5;
  const int t = threadIdx.x;
  const float fc[4] = {1.f, 3.f, 3.f, 1.f};

  for (int chunk = 0; chunk < 8; ++chunk) {
    const int c0 = ch * 128 + chunk * 16;
    __syncthreads();
    // stage: 2048 float4s = 8 per thread; f4 -> (c, r, w4)
#pragma unroll
    for (int i = 0; i < 8; ++i) {
      int f4 = t + 256 * i;
      int c = f4 >> 7, r = (f4 >> 4) & 7, w4 = f4 & 15;
      int hin = h0 - 2 + r;
      float4 v = make_float4(0.f, 0.f, 0.f, 0.f);
      if (hin >= 0 && hin < 64)
        v = ((const float4*)(x + ((size_t)((b * 256 + c0 + c) * 64 + hin) << 6)))[w4];
      ((float4*)sx)[f4] = v;
    }
    __syncthreads();
    // horizontal: st[c][r][jw] = sum_v fc[v]*sx[c][r][jw+v-2], jw in [0,65)
#pragma unroll
    for (int i = 0; i < 33; ++i) {
      int idx = t + 256 * i;               // 16*8*66 = 8448 exactly
      int c = idx / 528;
      int rm = idx - c * 528;
      int r = rm / 66;
      int jw = rm - r * 66;
      if (jw < 65) {
        float a = 0.f;
#pragma unroll
        for (int v = 0; v < 4; ++v) {
          int col = jw + v - 2;
          if (col >= 0 && col < 64) a += fc[v] * sx[(c * 8 + r) * 64 + col];
        }
        st[c * 529 + r * 66 + jw] = a;
      }
    }
    __syncthreads();
    // vertical + NHWC store: 5*65*16 = 5200 outputs
    for (int i = 0; i < 21; ++i) {
      int idx = t + 256 * i;
      if (idx >= 5200) break;
      int c = idx & 15;
      int hw = idx >> 4;
      int w = hw % 65;
      int h = hw / 65;
      float a = 0.f;
#pragma unroll
      for (int u = 0; u < 4; ++u) a += fc[u] * st[c * 529 + (h + u) * 66 + w];
      xft[((size_t)((b * 65 + h0 + h) * 65 + w) << 8) + c0 + c] = f2bf(a * 0.015625f);
    }
  }
}

// ---------------- Kernel 2: w[oc][ic][3][3] f32 -> wb[oc][j*256+ic] bf16 --------
__global__ __launch_bounds__(256) void k_wcast2(const float* __restrict__ w,
                                                ushort* __restrict__ wb) {
  int iw = blockIdx.x * 256 + threadIdx.x;   // 589824 elems, coalesced read
  float v = w[iw];
  int j = iw % 9;
  int t2 = iw / 9;
  int ic = t2 & 255;
  int oc = t2 >> 8;
  wb[oc * 2304 + j * 256 + ic] = f2bf(v);
}

// ---------------- Kernel 3: implicit-conv GEMM ----------------------------------
// C[oc=256][n=16384], K = 9 taps * 256 ic. 256 blocks of 512 thr (8 waves 2m x 4n),
// wave tile 64m x 32n, direct-global fragments, register double-buffer (k-step 64).
__global__ __launch_bounds__(512) void k_gemm2(const ushort* __restrict__ Wb,
                                               const ushort* __restrict__ Xt,
                                               const float* __restrict__ bias,
                                               float* __restrict__ out) {
  const int bid = blockIdx.x;                 // 0..255
  const int mtile = (bid >> 3) & 1;           // pair sharing n-panel lands same XCD
  const int ntile = ((bid >> 4) << 3) | (bid & 7);
  const int wid = threadIdx.x >> 6;
  const int lane = threadIdx.x & 63;
  const int wm = wid >> 2, wn = wid & 3;
  const int m0 = mtile * 128 + wm * 64;
  const int n0 = ntile * 128 + wn * 32;
  const int lrow = lane & 15;
  const int kgrp = lane >> 4;

  const ushort* ap[4];
#pragma unroll
  for (int f = 0; f < 4; ++f)
    ap[f] = Wb + (size_t)(m0 + f * 16 + lrow) * 2304 + kgrp * 8;

  size_t bb[2];
#pragma unroll
  for (int f = 0; f < 2; ++f) {
    int nn = n0 + f * 16 + lrow;
    int b = nn >> 10, oh = (nn >> 5) & 31, ow = nn & 31;
    bb[f] = ((size_t)((b * 65 + 2 * oh) * 65 + 2 * ow) << 8) + kgrp * 8;
  }

  f32x4 acc[4][2];
#pragma unroll
  for (int i = 0; i < 4; ++i)
#pragma unroll
    for (int jj = 0; jj < 2; ++jj) acc[i][jj] = (f32x4){0.f, 0.f, 0.f, 0.f};

  bf16x8 A0[4][2], B0[2][2], A1[4][2], B1[2][2];

#define LOADS(SA, SB, tt)                                                      \
  {                                                                            \
    const int j_ = (tt) >> 2;                                                  \
    const int dh_ = j_ / 3;                                                    \
    const int dw_ = j_ - 3 * dh_;                                              \
    const int joff_ = (dh_ * 65 + dw_) << 8;                                   \
    const int ic0_ = ((tt) & 3) << 6;                                          \
    _Pragma("unroll") for (int f = 0; f < 4; ++f) {                            \
      SA[f][0] = *(const bf16x8*)(ap[f] + (tt) * 64);                          \
      SA[f][1] = *(const bf16x8*)(ap[f] + (tt) * 64 + 32);                     \
    }                                                                          \
    _Pragma("unroll") for (int f = 0; f < 2; ++f) {                            \
      const ushort* p_ = Xt + bb[f] + joff_ + ic0_;                            \
      SB[f][0] = *(const bf16x8*)(p_);                                         \
      SB[f][1] = *(const bf16x8*)(p_ + 32);                                    \
    }                                                                          \
  }

#define MFMAS(SA, SB)                                                          \
  {                                                                            \
    _Pragma("unroll") for (int h = 0; h < 2; ++h)                              \
    _Pragma("unroll") for (int fm = 0; fm < 4; ++fm)                           \
    _Pragma("unroll") for (int fn = 0; fn < 2; ++fn)                           \
      acc[fm][fn] =                                                            \
          __builtin_amdgcn_mfma_f32_16x16x32_bf16(SA[fm][h], SB[fn][h],        \
                                                  acc[fm][fn], 0, 0, 0);       \
  }

  LOADS(A0, B0, 0);
  LOADS(A1, B1, 1);
  for (int t = 0; t < 36; t += 2) {
    MFMAS(A0, B0);
    if (t + 2 < 36) LOADS(A0, B0, t + 2);
    MFMAS(A1, B1);
    if (t + 3 < 36) LOADS(A1, B1, t + 3);
  }

  // epilogue: D row(oc) = m0+fm*16+4*kgrp+r, col(n) = n0+fn*16+lrow
  f32x4 bv[4];
#pragma unroll
  for (int fm = 0; fm < 4; ++fm)
    bv[fm] = *(const f32x4*)(bias + m0 + fm * 16 + kgrp * 4);

#pragma unroll
  for (int fm = 0; fm < 4; ++fm) {
#pragma unroll
    for (int fn = 0; fn < 2; ++fn) {
      int nn = n0 + fn * 16 + lrow;
      size_t ob = (size_t)(nn >> 10) * OUT_PER_B + (nn & 1023) +
                  (size_t)(m0 + fm * 16 + kgrp * 4) * 1024;
      float* op = out + ob;
      op[0]    = acc[fm][fn][0] + bv[fm][0];
      op[1024] = acc[fm][fn][1] + bv[fm][1];
      op[2048] = acc[fm][fn][2] + bv[fm][2];
      op[3072] = acc[fm][fn][3] + bv[fm][3];
    }
  }
}

extern "C" void kernel_launch(void* const* d_in, const int* in_sizes, int n_in,
                              void* d_out, int out_size, void* d_ws, size_t ws_size,
                              hipStream_t stream) {
  const float* x    = (const float*)d_in[0];  // [16,256,64,64]
  const float* w    = (const float*)d_in[1];  // [256,256,3,3]
  const float* bias = (const float*)d_in[2];  // [256]
  float* out = (float*)d_out;                 // [16,256,32,32]

  char* ws = (char*)d_ws;
  ushort* xft = (ushort*)ws;                        // 34,611,200 B
  ushort* wb  = (ushort*)(ws + 34611200);           //  1,179,648 B

  k_fir_nhwc<<<416, 256, 0, stream>>>(x, xft);
  k_wcast2<<<2304, 256, 0, stream>>>(w, wb);
  k_gemm2<<<256, 512, 0, stream>>>(wb, xft, bias, out);
}

// Round 3
// 96.262 us; speedup vs baseline: 2.8192x; 2.8192x over previous
//
#include <hip/hip_runtime.h>
#include <hip/hip_bf16.h>

typedef __attribute__((ext_vector_type(8))) short bf16x8;
typedef __attribute__((ext_vector_type(4))) float f32x4;

#define KD 2304
#define PL 4228                      // padded plane stride (elems) for xfn, 8B-aligned
#define OUT_PER_B (256 * 1024)

static __device__ __forceinline__ ushort f2bf(float f) {
  union { float f; unsigned int i; } v; v.f = f;
  unsigned int x = v.i;
  x += 0x7fffu + ((x >> 16) & 1u);   // round-to-nearest-even
  return (ushort)(x >> 16);
}

#define GLDS16(gp, lp)                                                         \
  __builtin_amdgcn_global_load_lds(                                            \
      (const __attribute__((address_space(1))) void*)(gp),                     \
      (__attribute__((address_space(3))) void*)(lp), 16, 0, 0)

// ---------------- Kernel 1: separable 4x4 FIR, pad 2, per (b,c) plane -----------
// f32 [64][64] -> bf16 [65][65] (flat, plane stride PL)
__global__ __launch_bounds__(256) void k_fir(const float* __restrict__ x,
                                             ushort* __restrict__ xfn) {
  __shared__ float sx[64 * 64];
  __shared__ float st[64 * 65];
  const int plane = blockIdx.x;               // 0..4095
  const float* xp = x + (size_t)plane * 4096;
  ushort* op = xfn + (size_t)plane * PL;
  const int t = threadIdx.x;

  const float4* x4 = (const float4*)xp;
  float4* s4 = (float4*)sx;
#pragma unroll
  for (int i = 0; i < 4; ++i) s4[t + 256 * i] = x4[t + 256 * i];
  __syncthreads();

  const float fc[4] = {1.f, 3.f, 3.f, 1.f};

  for (int idx = t; idx < 64 * 65; idx += 256) {
    int i = idx / 65, j = idx - i * 65;
    float a = 0.f;
#pragma unroll
    for (int v = 0; v < 4; ++v) {
      int col = j + v - 2;
      if (col >= 0 && col < 64) a += fc[v] * sx[i * 64 + col];
    }
    st[idx] = a;
  }
  __syncthreads();

  for (int idx = t; idx < 65 * 65; idx += 256) {
    int i = idx / 65, j = idx - i * 65;
    float a = 0.f;
#pragma unroll
    for (int u = 0; u < 4; ++u) {
      int r = i + u - 2;
      if (r >= 0 && r < 64) a += fc[u] * st[r * 65 + j];
    }
    op[idx] = f2bf(a * 0.015625f);            // contiguous 2B writes
  }
}

// ---------------- Kernel 2: transpose NCHW -> NHWC (bf16) -----------------------
// grid (67 hw-tiles, 4 c-tiles, 16 b); tile [64 c][64 hw] through LDS.
__global__ __launch_bounds__(256) void k_tr(const ushort* __restrict__ xfn,
                                            ushort* __restrict__ xft) {
  __shared__ ushort ld[64 * 68];              // pad 68: ushort4-aligned rows
  const int hw0 = blockIdx.x * 64;
  const int c0 = blockIdx.y * 64;
  const int b = blockIdx.z;
  const int t = threadIdx.x;

#pragma unroll
  for (int i = 0; i < 4; ++i) {
    int idx = i * 256 + t;                    // 0..1023
    int cl = idx >> 4, hw4 = idx & 15;
    const ushort* sp = xfn + (size_t)(b * 256 + c0 + cl) * PL + hw0 + hw4 * 4;
    *(ushort4*)&ld[cl * 68 + hw4 * 4] = *(const ushort4*)sp;  // safe: PL-padded
  }
  __syncthreads();
#pragma unroll
  for (int i = 0; i < 4; ++i) {
    int idx = i * 256 + t;
    int hwl = idx >> 4, c4 = idx & 15;
    int hw = hw0 + hwl;
    if (hw < 4225) {
      ushort4 v;
      v.x = ld[(c4 * 4 + 0) * 68 + hwl];
      v.y = ld[(c4 * 4 + 1) * 68 + hwl];
      v.z = ld[(c4 * 4 + 2) * 68 + hwl];
      v.w = ld[(c4 * 4 + 3) * 68 + hwl];
      *(ushort4*)&xft[((size_t)(b * 4225 + hw) << 8) + c0 + c4 * 4] = v;
    }
  }
}

// ---------------- Kernel 3: w[oc][ic][3][3] f32 -> wb[oc][j*256+ic] bf16 --------
__global__ __launch_bounds__(256) void k_wcast2(const float* __restrict__ w,
                                                ushort* __restrict__ wb) {
  int iw = blockIdx.x * 256 + threadIdx.x;
  float v = w[iw];
  int j = iw % 9;
  int t2 = iw / 9;
  int ic = t2 & 255;
  int oc = t2 >> 8;
  wb[oc * KD + j * 256 + ic] = f2bf(v);
}

// ---------------- Kernel 4: implicit-conv GEMM, m97 structure -------------------
// C[oc=256][n=16384]; BM=128, BN=64, BK=64; 256 thr (4 waves, 2m x 2n, 64x32 each)
// global_load_lds staging (linear dest + inverse-swz source), swizzled ds_read.
__global__ __launch_bounds__(256) void k_gemm3(const ushort* __restrict__ Wb,
                                               const ushort* __restrict__ Xt,
                                               const float* __restrict__ bias,
                                               float* __restrict__ out) {
  __shared__ ushort lA[128 * 64];
  __shared__ ushort lB[64 * 64];
  const int bid = blockIdx.x;                      // 0..511
  const int work = (bid & 7) * 64 + (bid >> 3);    // XCD-chunked (512%8==0, bijective)
  const int ntile = work >> 1;
  const int mtile = work & 1;
  const int m0 = mtile * 128;
  const int n0 = ntile * 64;
  const int t = threadIdx.x;
  const int wid = t >> 6, lane = t & 63;
  const int wm = wid >> 1, wn = wid & 1;
  const int lrow = lane & 15, kgrp = lane >> 4;
  const int sw = lrow & 7;

  // staging sources (pre-swizzled: lds col (idx&7) holds data col (idx&7)^(row&7))
  const ushort* aB[4];
#pragma unroll
  for (int i = 0; i < 4; ++i) {
    int idx = i * 256 + t;
    int row = idx >> 3;
    aB[i] = Wb + (size_t)(m0 + row) * KD + (((idx & 7) ^ (row & 7)) << 3);
  }
  const ushort* bB[2];
#pragma unroll
  for (int i = 0; i < 2; ++i) {
    int idx = i * 256 + t;
    int row = idx >> 3;
    int n = n0 + row;
    int b = n >> 10, oh = (n >> 5) & 31, ow = n & 31;
    bB[i] = Xt + ((size_t)((b * 65 + 2 * oh) * 65 + 2 * ow) << 8) +
            (((idx & 7) ^ (row & 7)) << 3);
  }

  f32x4 acc[4][2];
#pragma unroll
  for (int i = 0; i < 4; ++i)
#pragma unroll
    for (int j = 0; j < 2; ++j) acc[i][j] = (f32x4){0.f, 0.f, 0.f, 0.f};

  const int cA0 = ((kgrp ^ sw) << 3);              // swizzled read cols (ushorts)
  const int cA1 = (((kgrp + 4) ^ sw) << 3);

  for (int kt = 0; kt < 36; ++kt) {
    const int j = kt >> 2;
    const int dh = j / 3, dw = j - 3 * dh;
    const int boff = (dh * 65 + dw) * 256 + ((kt & 3) << 6);
    const int k0 = kt << 6;
    __syncthreads();
#pragma unroll
    for (int i = 0; i < 4; ++i)
      GLDS16(aB[i] + k0, &lA[(i * 256 + t) * 8]);
#pragma unroll
    for (int i = 0; i < 2; ++i)
      GLDS16(bB[i] + boff, &lB[(i * 256 + t) * 8]);
    __syncthreads();

    bf16x8 Af[4][2], Bf[2][2];
#pragma unroll
    for (int f = 0; f < 4; ++f) {
      int row = wm * 64 + f * 16 + lrow;
      Af[f][0] = *(const bf16x8*)&lA[row * 64 + cA0];
      Af[f][1] = *(const bf16x8*)&lA[row * 64 + cA1];
    }
#pragma unroll
    for (int f = 0; f < 2; ++f) {
      int row = wn * 32 + f * 16 + lrow;
      Bf[f][0] = *(const bf16x8*)&lB[row * 64 + cA0];
      Bf[f][1] = *(const bf16x8*)&lB[row * 64 + cA1];
    }
#pragma unroll
    for (int h = 0; h < 2; ++h)
#pragma unroll
      for (int fm = 0; fm < 4; ++fm)
#pragma unroll
        for (int fn = 0; fn < 2; ++fn)
          acc[fm][fn] = __builtin_amdgcn_mfma_f32_16x16x32_bf16(
              Af[fm][h], Bf[fn][h], acc[fm][fn], 0, 0, 0);
  }

  f32x4 bv[4];
#pragma unroll
  for (int fm = 0; fm < 4; ++fm)
    bv[fm] = *(const f32x4*)(bias + m0 + wm * 64 + fm * 16 + kgrp * 4);

#pragma unroll
  for (int fm = 0; fm < 4; ++fm) {
#pragma unroll
    for (int fn = 0; fn < 2; ++fn) {
      int nn = n0 + wn * 32 + fn * 16 + lrow;
      int oc = m0 + wm * 64 + fm * 16 + kgrp * 4;
      float* op = out + (size_t)(nn >> 10) * OUT_PER_B + (nn & 1023) +
                  (size_t)oc * 1024;
      op[0]    = acc[fm][fn][0] + bv[fm][0];
      op[1024] = acc[fm][fn][1] + bv[fm][1];
      op[2048] = acc[fm][fn][2] + bv[fm][2];
      op[3072] = acc[fm][fn][3] + bv[fm][3];
    }
  }
}

extern "C" void kernel_launch(void* const* d_in, const int* in_sizes, int n_in,
                              void* d_out, int out_size, void* d_ws, size_t ws_size,
                              hipStream_t stream) {
  const float* x    = (const float*)d_in[0];  // [16,256,64,64]
  const float* w    = (const float*)d_in[1];  // [256,256,3,3]
  const float* bias = (const float*)d_in[2];  // [256]
  float* out = (float*)d_out;                 // [16,256,32,32]

  char* ws = (char*)d_ws;
  ushort* xfn = (ushort*)ws;                        // 4096*4228*2 = 34,635,776 B
  ushort* xft = (ushort*)(ws + 34635776);           // 16*4225*256*2 = 34,611,200 B
  ushort* wb  = (ushort*)(ws + 34635776 + 34611200);// 1,179,648 B

  k_fir<<<4096, 256, 0, stream>>>(x, xfn);
  k_tr<<<dim3(67, 4, 16), 256, 0, stream>>>(xfn, xft);
  k_wcast2<<<2304, 256, 0, stream>>>(w, wb);
  k_gemm3<<<512, 256, 0, stream>>>(wb, xft, bias, out);
}

// Round 4
// 76.555 us; speedup vs baseline: 3.5449x; 1.2574x over previous
//
#include <hip/hip_runtime.h>
#include <hip/hip_bf16.h>

typedef __attribute__((ext_vector_type(8))) short bf16x8;
typedef __attribute__((ext_vector_type(4))) float f32x4;

#define KD 2304
#define PL 4228                      // padded plane stride (elems) for xfn, 8B-aligned
#define OUT_PER_B (256 * 1024)

static __device__ __forceinline__ ushort f2bf(float f) {
  union { float f; unsigned int i; } v; v.f = f;
  unsigned int x = v.i;
  x += 0x7fffu + ((x >> 16) & 1u);   // round-to-nearest-even
  return (ushort)(x >> 16);
}

#define GLDS16(gp, lp)                                                         \
  __builtin_amdgcn_global_load_lds(                                            \
      (const __attribute__((address_space(1))) void*)(gp),                     \
      (__attribute__((address_space(3))) void*)(lp), 16, 0, 0)

// ---------------- Kernel 1: separable 4x4 FIR, pad 2, per (b,c) plane -----------
// f32 [64][64] -> bf16 [65][65] (flat, plane stride PL). Branch-free via halos.
// sxp stride 71: staging stores are 2-way/bank (free); stp stride 66.
__global__ __launch_bounds__(256) void k_fir(const float* __restrict__ x,
                                             ushort* __restrict__ xfn) {
  __shared__ float sxp[64 * 71];   // [row][2+col], cols 0,1,66,67 = zero halo
  __shared__ float stp[68 * 66];   // [2+hrow][col], rows 0,1,66,67 = zero halo
  const int plane = blockIdx.x;               // 0..4095
  const float* xp = x + (size_t)plane * 4096;
  ushort* op = xfn + (size_t)plane * PL;
  const int t = threadIdx.x;

  // zero halos: sxp 64 rows x 4 cols (exactly 256), stp 4 rows x 66 cols
  {
    int r = t & 63;
    int cs = t >> 6;
    int col = (cs < 2) ? cs : (64 + cs);      // 0,1,66,67
    sxp[r * 71 + col] = 0.f;
  }
  for (int i = t; i < 264; i += 256) {
    int rr = i / 66;                          // 0..3
    int cc = i - rr * 66;
    int row = (rr < 2) ? rr : (64 + rr);      // 0,1,66,67
    stp[row * 66 + cc] = 0.f;
  }

  // stage plane: 1024 float4, 4 per thread
  const float4* x4 = (const float4*)xp;
#pragma unroll
  for (int i = 0; i < 4; ++i) {
    int f4 = t + 256 * i;
    int r = f4 >> 4, w4 = f4 & 15;
    float4 v = x4[f4];
    float* d = &sxp[r * 71 + 2 + w4 * 4];
    d[0] = v.x; d[1] = v.y; d[2] = v.z; d[3] = v.w;
  }
  __syncthreads();

  // horizontal: out_h[i][j] = x[j-2] + 3x[j-1] + 3x[j] + x[j+1], 64 x 65
  for (int idx = t; idx < 4160; idx += 256) {
    int i = idx / 65, j = idx - i * 65;
    const float* s = &sxp[i * 71 + j];        // x[j-2] sits at sxp col j
    stp[(i + 2) * 66 + j] = (s[0] + s[3]) + 3.f * (s[1] + s[2]);
  }
  __syncthreads();

  // vertical + store: 65 x 65, branch-free
  for (int idx = t; idx < 4225; idx += 256) {
    int i = idx / 65, j = idx - i * 65;
    const float* s = &stp[i * 66 + j];        // h[i-2] sits at stp row i
    float a = (s[0] + s[3 * 66]) + 3.f * (s[66] + s[2 * 66]);
    op[idx] = f2bf(a * 0.015625f);
  }
}

// ---------------- Kernel 2: transpose NCHW -> NHWC (bf16) -----------------------
// grid (67 hw-tiles, 4 c-tiles, 16 b); tile [64 c][64 hw] through LDS.
__global__ __launch_bounds__(256) void k_tr(const ushort* __restrict__ xfn,
                                            ushort* __restrict__ xft) {
  __shared__ ushort ld[64 * 68];              // pad 68: ushort4-aligned rows
  const int hw0 = blockIdx.x * 64;
  const int c0 = blockIdx.y * 64;
  const int b = blockIdx.z;
  const int t = threadIdx.x;

#pragma unroll
  for (int i = 0; i < 4; ++i) {
    int idx = i * 256 + t;                    // 0..1023
    int cl = idx >> 4, hw4 = idx & 15;
    const ushort* sp = xfn + (size_t)(b * 256 + c0 + cl) * PL + hw0 + hw4 * 4;
    *(ushort4*)&ld[cl * 68 + hw4 * 4] = *(const ushort4*)sp;  // safe: PL-padded
  }
  __syncthreads();
#pragma unroll
  for (int i = 0; i < 4; ++i) {
    int idx = i * 256 + t;
    int hwl = idx >> 4, c4 = idx & 15;
    int hw = hw0 + hwl;
    if (hw < 4225) {
      ushort4 v;
      v.x = ld[(c4 * 4 + 0) * 68 + hwl];
      v.y = ld[(c4 * 4 + 1) * 68 + hwl];
      v.z = ld[(c4 * 4 + 2) * 68 + hwl];
      v.w = ld[(c4 * 4 + 3) * 68 + hwl];
      *(ushort4*)&xft[((size_t)(b * 4225 + hw) << 8) + c0 + c4 * 4] = v;
    }
  }
}

// ---------------- Kernel 3: w[oc][ic][3][3] f32 -> wb[oc][j*256+ic] bf16 --------
__global__ __launch_bounds__(256) void k_wcast2(const float* __restrict__ w,
                                                ushort* __restrict__ wb) {
  int iw = blockIdx.x * 256 + threadIdx.x;
  float v = w[iw];
  int j = iw % 9;
  int t2 = iw / 9;
  int ic = t2 & 255;
  int oc = t2 >> 8;
  wb[oc * KD + j * 256 + ic] = f2bf(v);
}

// ---------------- Kernel 4: implicit-conv GEMM, m97 structure -------------------
// C[oc=256][n=16384]; BM=128, BN=64, BK=64; 256 thr (4 waves, 2m x 2n, 64x32 each)
// global_load_lds staging (linear dest + inverse-swz source), swizzled ds_read.
__global__ __launch_bounds__(256) void k_gemm3(const ushort* __restrict__ Wb,
                                               const ushort* __restrict__ Xt,
                                               const float* __restrict__ bias,
                                               float* __restrict__ out) {
  __shared__ ushort lA[128 * 64];
  __shared__ ushort lB[64 * 64];
  const int bid = blockIdx.x;                      // 0..511
  const int work = (bid & 7) * 64 + (bid >> 3);    // XCD-chunked (512%8==0, bijective)
  const int ntile = work >> 1;
  const int mtile = work & 1;
  const int m0 = mtile * 128;
  const int n0 = ntile * 64;
  const int t = threadIdx.x;
  const int wid = t >> 6, lane = t & 63;
  const int wm = wid >> 1, wn = wid & 1;
  const int lrow = lane & 15, kgrp = lane >> 4;
  const int sw = lrow & 7;

  // staging sources (pre-swizzled: lds col (idx&7) holds data col (idx&7)^(row&7))
  const ushort* aB[4];
#pragma unroll
  for (int i = 0; i < 4; ++i) {
    int idx = i * 256 + t;
    int row = idx >> 3;
    aB[i] = Wb + (size_t)(m0 + row) * KD + (((idx & 7) ^ (row & 7)) << 3);
  }
  const ushort* bB[2];
#pragma unroll
  for (int i = 0; i < 2; ++i) {
    int idx = i * 256 + t;
    int row = idx >> 3;
    int n = n0 + row;
    int b = n >> 10, oh = (n >> 5) & 31, ow = n & 31;
    bB[i] = Xt + ((size_t)((b * 65 + 2 * oh) * 65 + 2 * ow) << 8) +
            (((idx & 7) ^ (row & 7)) << 3);
  }

  f32x4 acc[4][2];
#pragma unroll
  for (int i = 0; i < 4; ++i)
#pragma unroll
    for (int j = 0; j < 2; ++j) acc[i][j] = (f32x4){0.f, 0.f, 0.f, 0.f};

  const int cA0 = ((kgrp ^ sw) << 3);              // swizzled read cols (ushorts)
  const int cA1 = (((kgrp + 4) ^ sw) << 3);

  for (int kt = 0; kt < 36; ++kt) {
    const int j = kt >> 2;
    const int dh = j / 3, dw = j - 3 * dh;
    const int boff = (dh * 65 + dw) * 256 + ((kt & 3) << 6);
    const int k0 = kt << 6;
    __syncthreads();
#pragma unroll
    for (int i = 0; i < 4; ++i)
      GLDS16(aB[i] + k0, &lA[(i * 256 + t) * 8]);
#pragma unroll
    for (int i = 0; i < 2; ++i)
      GLDS16(bB[i] + boff, &lB[(i * 256 + t) * 8]);
    __syncthreads();

    bf16x8 Af[4][2], Bf[2][2];
#pragma unroll
    for (int f = 0; f < 4; ++f) {
      int row = wm * 64 + f * 16 + lrow;
      Af[f][0] = *(const bf16x8*)&lA[row * 64 + cA0];
      Af[f][1] = *(const bf16x8*)&lA[row * 64 + cA1];
    }
#pragma unroll
    for (int f = 0; f < 2; ++f) {
      int row = wn * 32 + f * 16 + lrow;
      Bf[f][0] = *(const bf16x8*)&lB[row * 64 + cA0];
      Bf[f][1] = *(const bf16x8*)&lB[row * 64 + cA1];
    }
#pragma unroll
    for (int h = 0; h < 2; ++h)
#pragma unroll
      for (int fm = 0; fm < 4; ++fm)
#pragma unroll
        for (int fn = 0; fn < 2; ++fn)
          acc[fm][fn] = __builtin_amdgcn_mfma_f32_16x16x32_bf16(
              Af[fm][h], Bf[fn][h], acc[fm][fn], 0, 0, 0);
  }

  f32x4 bv[4];
#pragma unroll
  for (int fm = 0; fm < 4; ++fm)
    bv[fm] = *(const f32x4*)(bias + m0 + wm * 64 + fm * 16 + kgrp * 4);

#pragma unroll
  for (int fm = 0; fm < 4; ++fm) {
#pragma unroll
    for (int fn = 0; fn < 2; ++fn) {
      int nn = n0 + wn * 32 + fn * 16 + lrow;
      int oc = m0 + wm * 64 + fm * 16 + kgrp * 4;
      float* op = out + (size_t)(nn >> 10) * OUT_PER_B + (nn & 1023) +
                  (size_t)oc * 1024;
      op[0]    = acc[fm][fn][0] + bv[fm][0];
      op[1024] = acc[fm][fn][1] + bv[fm][1];
      op[2048] = acc[fm][fn][2] + bv[fm][2];
      op[3072] = acc[fm][fn][3] + bv[fm][3];
    }
  }
}

extern "C" void kernel_launch(void* const* d_in, const int* in_sizes, int n_in,
                              void* d_out, int out_size, void* d_ws, size_t ws_size,
                              hipStream_t stream) {
  const float* x    = (const float*)d_in[0];  // [16,256,64,64]
  const float* w    = (const float*)d_in[1];  // [256,256,3,3]
  const float* bias = (const float*)d_in[2];  // [256]
  float* out = (float*)d_out;                 // [16,256,32,32]

  char* ws = (char*)d_ws;
  ushort* xfn = (ushort*)ws;                        // 4096*4228*2 = 34,635,776 B
  ushort* xft = (ushort*)(ws + 34635776);           // 16*4225*256*2 = 34,611,200 B
  ushort* wb  = (ushort*)(ws + 34635776 + 34611200);// 1,179,648 B

  k_fir<<<4096, 256, 0, stream>>>(x, xfn);
  k_tr<<<dim3(67, 4, 16), 256, 0, stream>>>(xfn, xft);
  k_wcast2<<<2304, 256, 0, stream>>>(w, wb);
  k_gemm3<<<512, 256, 0, stream>>>(wb, xft, bias, out);
}